// Round 4
// baseline (719.652 us; speedup 1.0000x reference)
//
#include <hip/hip_runtime.h>
#include <cstdint>
#include <cstddef>

// Problem constants: BS=512, EN=512, SEQ=64, D_ENT=256, D_IN=1024, D_KEY=32, D_F=256, H=32
//
// Algebraic restructure (this round): ae is consumed only via ae@q1w+q1b, so
//   AE@q1w + q1b = P0 + Z1@(e2w@q1w) + e2b@q1w,  P0 = ar@q1w + q1b
// which deletes the two big GEMMs (Z1@e2w -> AE, AE@q1w) and the 67MB AE buffer.

typedef short bf16x8 __attribute__((ext_vector_type(8)));
typedef float f32x4  __attribute__((ext_vector_type(4)));

// fp32->bf16 via hardware v_cvt_pk_bf16_f32 (RNE, gfx950).
__device__ __forceinline__ unsigned f2bf2(float lo, float hi) {
    unsigned r;
    asm("v_cvt_pk_bf16_f32 %0, %1, %2" : "=v"(r) : "v"(lo), "v"(hi));
    return r;
}
__device__ __forceinline__ ushort f2bf(float f) {
    unsigned r;
    asm("v_cvt_pk_bf16_f32 %0, %1, %1" : "=v"(r) : "v"(f));
    return (ushort)r;
}

__device__ __forceinline__ void gld16(const void* g, void* l) {
    __builtin_amdgcn_global_load_lds(
        (const __attribute__((address_space(1))) void*)g,
        (__attribute__((address_space(3))) void*)l,
        16, 0, 0);
}

// ---------------------------------------------------------------------------
// bf16 MFMA GEMM: out = relu_post(A[M,K] @ B[K,N] + bias [+ addvec]).
// B pre-transposed as BT[N,K] bf16. A bf16 (global_load_lds) or fp32 (cvt).
// KEYMODE remaps out row r into key layout [b][513][32].
// Chunk-XOR swizzle (both sides, rule #21) keeps ds_read_b128 conflict-free.
// ---------------------------------------------------------------------------
template<int BM, int BN, int BK, int WR, int WC,
         bool RELU, bool ADDVEC, bool OUT_BF16, bool A_F32, bool KEYMODE>
__global__ __launch_bounds__(WR * WC * 64)
void mfma_gemm(const void* __restrict__ Av, int lda,
               const ushort* __restrict__ BT,
               const float* __restrict__ bias,
               const float* __restrict__ addvec, int ldadd,
               void* __restrict__ outv, int ldo,
               int K, int out_row_offset)
{
    constexpr int NT  = WR * WC * 64;
    constexpr int WM  = BM / WR, WN = BN / WC;
    constexpr int TMt = WM / 16, TNt = WN / 16;
    constexpr int KC  = BK / 8;          // 16B chunks per row
    constexpr int SWZ = KC - 1;          // chunk-XOR mask
    constexpr int CHA = BM * KC, CHB = BN * KC;
    __shared__ __align__(16) ushort As[BM * BK];
    __shared__ __align__(16) ushort Bs[BN * BK];

    const int tid  = threadIdx.x;
    const int lane = tid & 63;
    const int w    = tid >> 6;
    const int wr   = w / WC, wc = w % WC;
    const int row0 = blockIdx.x * BM;
    const int n0   = blockIdx.y * BN;

    f32x4 acc[TMt][TNt];
#pragma unroll
    for (int i = 0; i < TMt; i++)
#pragma unroll
        for (int j = 0; j < TNt; j++)
#pragma unroll
            for (int r = 0; r < 4; r++) acc[i][j][r] = 0.f;

    const ushort* Ab = (const ushort*)Av;
    const float*  Af = (const float*)Av;

    for (int k0 = 0; k0 < K; k0 += BK) {
        if (A_F32) {
#pragma unroll
            for (int id = tid; id < CHA; id += NT) {
                int r = id / KC, kc = id % KC;
                int kcs = kc ^ (r & SWZ);      // source chunk (swizzled)
                const float* src = Af + (size_t)(row0 + r) * lda + k0 + kcs * 8;
                float4 v0 = *(const float4*)(src);
                float4 v1 = *(const float4*)(src + 4);
                uint4 p;
                p.x = f2bf2(v0.x, v0.y);
                p.y = f2bf2(v0.z, v0.w);
                p.z = f2bf2(v1.x, v1.y);
                p.w = f2bf2(v1.z, v1.w);
                *(uint4*)(&As[id * 8]) = p;
            }
        } else {
#pragma unroll
            for (int id = tid; id < CHA; id += NT) {
                int r = id / KC, kc = id % KC;
                int kcs = kc ^ (r & SWZ);
                gld16(Ab + (size_t)(row0 + r) * lda + k0 + kcs * 8, &As[id * 8]);
            }
        }
#pragma unroll
        for (int id = tid; id < CHB; id += NT) {
            int r = id / KC, kc = id % KC;
            int kcs = kc ^ (r & SWZ);
            gld16(BT + (size_t)(n0 + r) * K + k0 + kcs * 8, &Bs[id * 8]);
        }
        __syncthreads();

        const int m16 = lane & 15;
        const int hi  = lane >> 4;
#pragma unroll
        for (int kk = 0; kk < BK / 32; kk++) {
            bf16x8 afr[TMt], bfr[TNt];
#pragma unroll
            for (int tm = 0; tm < TMt; tm++) {
                int row = wr * WM + tm * 16 + m16;
                int cc  = kk * 4 + hi;
                afr[tm] = *(bf16x8*)(&As[row * BK + ((cc ^ (row & SWZ)) << 3)]);
            }
#pragma unroll
            for (int tn = 0; tn < TNt; tn++) {
                int row = wc * WN + tn * 16 + m16;
                int cc  = kk * 4 + hi;
                bfr[tn] = *(bf16x8*)(&Bs[row * BK + ((cc ^ (row & SWZ)) << 3)]);
            }
#pragma unroll
            for (int tm = 0; tm < TMt; tm++)
#pragma unroll
                for (int tn = 0; tn < TNt; tn++)
                    acc[tm][tn] = __builtin_amdgcn_mfma_f32_16x16x32_bf16(
                        afr[tm], bfr[tn], acc[tm][tn], 0, 0, 0);
        }
        __syncthreads();
    }

    // Epilogue. C layout: col = lane&15, row = (lane>>4)*4 + reg
    // NOTE: RELU applied AFTER addvec (needed by the fused Y1 GEMM).
    float*  outf = (float*)outv;
    ushort* outh = (ushort*)outv;
    const int cn = lane & 15;
    const int rb = (lane >> 4) * 4;
#pragma unroll
    for (int tm = 0; tm < TMt; tm++) {
#pragma unroll
        for (int r = 0; r < 4; r++) {
            int grow = row0 + wr * WM + tm * 16 + rb + r;
            int b_   = grow & 511;
#pragma unroll
            for (int tn = 0; tn < TNt; tn++) {
                int gcol = n0 + wc * WN + tn * 16 + cn;
                float v = acc[tm][tn][r] + bias[gcol];
                if (ADDVEC) v += addvec[(size_t)b_ * ldadd + gcol];
                if (RELU)   v = fmaxf(v, 0.f);
                size_t oidx;
                if (KEYMODE) oidx = ((size_t)(grow >> 9) * 513 + b_) * 32 + gcol;
                else         oidx = (size_t)(grow + out_row_offset) * ldo + gcol;
                if (OUT_BF16) outh[oidx] = f2bf(v);
                else          outf[oidx] = v;
            }
        }
    }
}

// ---------------------------------------------------------------------------
// misc_prep: e2w bf16 copy (blocks 0..255), zeros (256), weight transposes
// (257..536), c2 = e2b@q1w (537).
// ---------------------------------------------------------------------------
__global__ __launch_bounds__(256) void misc_prep(
    const float* __restrict__ kw,  const float* __restrict__ e1w,
    const float* __restrict__ e2w, const float* __restrict__ q1w,
    const float* __restrict__ q2w, const float* __restrict__ e2b,
    ushort* __restrict__ kwt,  ushort* __restrict__ e1wt,
    ushort* __restrict__ e2wb, ushort* __restrict__ q1wt,
    ushort* __restrict__ q2wt,
    float* __restrict__ zeros, float* __restrict__ c2)
{
    int bx = blockIdx.x;
    if (bx < 256) {            // e2wb: straight f32->bf16 copy of e2w [256x1024]
        int i = (bx * 256 + threadIdx.x) * 4;
        float4 v = *(const float4*)(e2w + i);
        uint2 o;
        o.x = f2bf2(v.x, v.y);
        o.y = f2bf2(v.z, v.w);
        *(uint2*)(e2wb + i) = o;
        return;
    }
    if (bx == 256) {           // zero bias vector
        zeros[threadIdx.x] = 0.f;
        return;
    }
    if (bx == 537) {           // c2[j] = sum_k e2b[k] * q1w[k][j]
        int j = threadIdx.x;
        float acc = 0.f;
#pragma unroll 16
        for (int k = 0; k < 1024; k++) acc += e2b[k] * q1w[k * 256 + j];
        c2[j] = acc;
        return;
    }
    int bx2 = bx - 257;
    const float* W; ushort* WT; int K, N, t0;
    if      (bx2 < 8)   { W = kw;  WT = kwt;  K = 256;  N = 32;   t0 = bx2; }
    else if (bx2 < 16)  { W = e1w; WT = e1wt; K = 32;   N = 256;  t0 = bx2 - 8; }
    else if (bx2 < 272) { W = q1w; WT = q1wt; K = 1024; N = 256;  t0 = bx2 - 16; }
    else                { W = q2w; WT = q2wt; K = 256;  N = 32;   t0 = bx2 - 272; }
    int nn = N >> 5;
    int kt = (t0 / nn) * 32, nt = (t0 % nn) * 32;
    __shared__ float t[32][33];
    int x = threadIdx.x & 31, y = threadIdx.x >> 5;
    for (int i = y; i < 32; i += 8) t[i][x] = W[(size_t)(kt + i) * N + nt + x];
    __syncthreads();
    for (int i = y; i < 32; i += 8) WT[(size_t)(nt + i) * K + kt + x] = f2bf(t[x][i]);
}

// ---------------------------------------------------------------------------
// relu_y0: Y1 rows 0..511 = bf16(relu(P0))   (step 0: ae = ar)
// ---------------------------------------------------------------------------
__global__ __launch_bounds__(256) void relu_y0(
    const float* __restrict__ P0, ushort* __restrict__ Y1)
{
    int i = (blockIdx.x * 256 + threadIdx.x) * 8;
    float4 a = *(const float4*)(P0 + i);
    float4 b = *(const float4*)(P0 + i + 4);
    uint4 o;
    o.x = f2bf2(fmaxf(a.x, 0.f), fmaxf(a.y, 0.f));
    o.y = f2bf2(fmaxf(a.z, 0.f), fmaxf(a.w, 0.f));
    o.z = f2bf2(fmaxf(b.x, 0.f), fmaxf(b.y, 0.f));
    o.w = f2bf2(fmaxf(b.z, 0.f), fmaxf(b.w, 0.f));
    *(uint4*)(Y1 + i) = o;
}

// ---------------------------------------------------------------------------
// prep: key fixup + first-occurrence fs[b][n] + end step T + pooled EMB (bf16)
// ---------------------------------------------------------------------------
__global__ __launch_bounds__(64) void prep_kernel(
    const int* __restrict__ en_g, const int* __restrict__ su_g,
    const int* __restrict__ sun_g, float* __restrict__ key,
    const float* __restrict__ eemb,
    int* __restrict__ fs_g, ushort* __restrict__ EMB)
{
    int b = blockIdx.x;
    int tid = threadIdx.x;   // 64 = one wave
    __shared__ int fs_l[513];
    __shared__ int su_l[64];
    __shared__ float krows[64 * 32];
    for (int i = tid; i < 513; i += 64) fs_l[i] = 64;
    su_l[tid] = su_g[b * 64 + tid];
    int en = en_g[b];
    if (tid < 32) key[((size_t)b * 513 + 512) * 32 + tid] = 0.f;
    else          key[((size_t)b * 513 + en) * 32 + (tid - 32)] = eemb[tid - 32];
    __syncthreads();
    atomicMin(&fs_l[su_l[tid]], tid);
    unsigned long long ball = __ballot(su_l[tid] == en);
    int T = ball ? (__ffsll(ball) - 1) : 64;
    __syncthreads();
    {
        int d = tid & 31;
#pragma unroll 4
        for (int i = 0; i < 32; i++) {
            int r = 2 * i + (tid >> 5);
            krows[r * 32 + d] = key[((size_t)b * 513 + su_l[r]) * 32 + d];
        }
    }
    for (int i = tid; i < 513; i += 64) fs_g[(size_t)b * 513 + i] = fs_l[i];
    __syncthreads();

    int sun = sun_g[b];
    float a = 0.f;
    int cnt = 0;
    for (int i = 0; i < 64; i++) {
        bool nw = (i < T) && (fs_l[su_l[i]] == i);
        if (nw) {
            cnt++;
            if (tid < 32) a += krows[i * 32 + tid];
        }
        float denom = (sun != 0 && cnt > 0) ? (float)cnt : 1.0f;
        if (tid < 32) EMB[((size_t)i * 512 + b) * 32 + tid] = f2bf(a / denom);
    }
}

// ---------------------------------------------------------------------------
// LN-LSTM: one WAVE per batch, no barriers in the step loop.
// ---------------------------------------------------------------------------
__device__ inline float sigm(float x) { return 1.0f / (1.0f + expf(-x)); }

__global__ __launch_bounds__(128) void lstm_kernel(
    const float* __restrict__ X, const float* __restrict__ wih_g,
    const float* __restrict__ whh_g,
    const float* __restrict__ lnig, const float* __restrict__ lnib,
    const float* __restrict__ lnhg, const float* __restrict__ lnhb,
    const float* __restrict__ lncg, const float* __restrict__ lncb,
    float* __restrict__ Q)
{
    const int wv = threadIdx.x >> 6;
    const int lane = threadIdx.x & 63;
    const int b = blockIdx.x * 2 + wv;
    __shared__ float xs[2][64 * 32];

    {
        int d = lane & 31;
#pragma unroll 8
        for (int i = 0; i < 32; i++) {
            int s = 2 * i + (lane >> 5);
            xs[wv][s * 32 + d] = X[((size_t)s * 512 + b) * 32 + d];
        }
    }
    float w0[32], w1[32], u0[32], u1[32];
#pragma unroll
    for (int k = 0; k < 32; k++) {
        w0[k] = wih_g[k * 128 + lane];
        w1[k] = wih_g[k * 128 + lane + 64];
        u0[k] = whh_g[k * 128 + lane];
        u1[k] = whh_g[k * 128 + lane + 64];
    }
    const float gi0 = lnig[lane], gi1 = lnig[lane + 64];
    const float bi0 = lnib[lane], bi1 = lnib[lane + 64];
    const float gh0 = lnhg[lane], gh1 = lnhg[lane + 64];
    const float bh0 = lnhb[lane], bh1 = lnhb[lane + 64];
    const int j = lane & 31;
    const float gc = lncg[j], bc = lncb[j];
    float h = 0.f, c = 0.f;
    __syncthreads();

    const float* xrow = &xs[wv][0];
    for (int s = 0; s < 64; s++) {
        float ax0 = 0.f, ax1 = 0.f, ah0 = 0.f, ah1 = 0.f;
#pragma unroll
        for (int k = 0; k < 32; k++) {
            float xk = xrow[s * 32 + k];
            float hk = __shfl(h, k);
            ax0 += xk * w0[k]; ax1 += xk * w1[k];
            ah0 += hk * u0[k]; ah1 += hk * u1[k];
        }
        float r0 = ax0 + ax1, r1 = ax0 * ax0 + ax1 * ax1;
        float r2 = ah0 + ah1, r3 = ah0 * ah0 + ah1 * ah1;
#pragma unroll
        for (int m = 1; m <= 32; m <<= 1) {
            r0 += __shfl_xor(r0, m); r1 += __shfl_xor(r1, m);
            r2 += __shfl_xor(r2, m); r3 += __shfl_xor(r3, m);
        }
        float mx = r0 * (1.f / 128.f), vx = r1 * (1.f / 128.f) - mx * mx;
        float mh = r2 * (1.f / 128.f), vh = r3 * (1.f / 128.f) - mh * mh;
        float sx = rsqrtf(vx + 1e-5f), sh = rsqrtf(vh + 1e-5f);
        float g0 = (ax0 - mx) * sx * gi0 + bi0 + (ah0 - mh) * sh * gh0 + bh0;
        float g1 = (ax1 - mx) * sx * gi1 + bi1 + (ah1 - mh) * sh * gh1 + bh1;
        float igv = __shfl(g0, j),      fgv = __shfl(g0, j + 32);
        float cgv = __shfl(g1, j),      ogv = __shfl(g1, j + 32);
        float cc = sigm(fgv) * c + sigm(igv) * tanhf(cgv);
        float s0 = cc, s1 = cc * cc;
#pragma unroll
        for (int m = 1; m <= 32; m <<= 1) {
            s0 += __shfl_xor(s0, m); s1 += __shfl_xor(s1, m);
        }
        float mc = s0 * (1.f / 64.f), vc = s1 * (1.f / 64.f) - mc * mc;
        c = (cc - mc) * rsqrtf(vc + 1e-5f) * gc + bc;
        h = sigm(ogv) * tanhf(c);
        if (lane < 32) Q[((size_t)b * 64 + s) * 32 + lane] = h;
    }
}

// ---------------------------------------------------------------------------
// logits: out[b][s][n] = mask ? dot(Q[b][s], key[b][n]) : -1e9
// ---------------------------------------------------------------------------
__global__ __launch_bounds__(128) void logits_kernel(
    const float* __restrict__ key, const float* __restrict__ Q,
    const int* __restrict__ fs_g, const int* __restrict__ en_g,
    float* __restrict__ out)
{
    int b = blockIdx.x;
    int n0 = blockIdx.y * 128;
    int tid = threadIdx.x;
    __shared__ float Qs[64 * 32];
    __shared__ float Ks[128 * 33];
    for (int i = tid * 4; i < 2048; i += 512)
        *(float4*)(&Qs[i]) = *(const float4*)(Q + (size_t)b * 2048 + i);
    for (int i = tid; i < 4096; i += 128) {
        int r = i >> 5, d = i & 31;
        int n = n0 + r;
        Ks[r * 33 + d] = (n < 513) ? key[((size_t)b * 513 + n) * 32 + d] : 0.f;
    }
    __syncthreads();
    int n = n0 + tid;
    if (n < 513) {
        int en = en_g[b];
        int f = fs_g[(size_t)b * 513 + n];
        float kreg[32];
#pragma unroll
        for (int d = 0; d < 32; d++) kreg[d] = Ks[tid * 33 + d];
        for (int s = 0; s < 64; s++) {
            float a = 0.f;
#pragma unroll
            for (int d4 = 0; d4 < 8; d4++) {
                f32x4 qv = *(const f32x4*)(&Qs[s * 32 + d4 * 4]);
                a += qv[0] * kreg[d4 * 4 + 0] + qv[1] * kreg[d4 * 4 + 1]
                   + qv[2] * kreg[d4 * 4 + 2] + qv[3] * kreg[d4 * 4 + 3];
            }
            bool m = (s == 0) ? (n < en) : ((n <= en) && (f >= s));
            out[((size_t)b * 64 + s) * 513 + n] = m ? a : -1e9f;
        }
    }
}

// ---------------------------------------------------------------------------
extern "C" void kernel_launch(void* const* d_in, const int* in_sizes, int n_in,
                              void* d_out, int out_size, void* d_ws, size_t ws_size,
                              hipStream_t stream)
{
    const float* ee   = (const float*)d_in[0];
    const float* ar   = (const float*)d_in[1];
    const int*   en   = (const int*)d_in[2];
    const int*   su   = (const int*)d_in[3];
    const int*   sun  = (const int*)d_in[4];
    const float* kw   = (const float*)d_in[5];
    const float* kb   = (const float*)d_in[6];
    const float* q1w  = (const float*)d_in[7];
    const float* q1b  = (const float*)d_in[8];
    const float* q2w  = (const float*)d_in[9];
    const float* q2b  = (const float*)d_in[10];
    const float* e1w  = (const float*)d_in[11];
    const float* e1b  = (const float*)d_in[12];
    const float* e2w  = (const float*)d_in[13];
    const float* e2b  = (const float*)d_in[14];
    const float* eemb = (const float*)d_in[15];
    const float* wih  = (const float*)d_in[16];
    const float* whh  = (const float*)d_in[17];
    const float* lnig = (const float*)d_in[18];
    const float* lnib = (const float*)d_in[19];
    const float* lnhg = (const float*)d_in[20];
    const float* lnhb = (const float*)d_in[21];
    const float* lncg = (const float*)d_in[22];
    const float* lncb = (const float*)d_in[23];
    float* outp = (float*)d_out;

    char* p = (char*)d_ws;
    float*  key  = (float*)p;  p += (size_t)512 * 513 * 32 * 4;   // 33.6 MB
    float*  X    = (float*)p;  p += (size_t)32768 * 32 * 4;       // 4 MB
    float*  Q    = (float*)p;  p += (size_t)32768 * 32 * 4;       // 4 MB
    float*  P0   = (float*)p;  p += (size_t)512 * 256 * 4;        // 0.5 MB
    float*  c2   = (float*)p;  p += 256 * 4;
    float*  zeros= (float*)p;  p += 256 * 4;
    int*    fs   = (int*)p;    p += (size_t)512 * 513 * 4;        // 1.05 MB
    ushort* Z1b  = (ushort*)p; p += (size_t)32768 * 256 * 2;      // 16.8 MB
    ushort* Y1b  = (ushort*)p; p += (size_t)32768 * 256 * 2;      // 16.8 MB
    ushort* EMBb = (ushort*)p; p += (size_t)32768 * 32 * 2;       // 2 MB
    ushort* W2t  = (ushort*)p; p += (size_t)256 * 256 * 2;
    ushort* kwt  = (ushort*)p; p += (size_t)32 * 256 * 2;
    ushort* e1wt = (ushort*)p; p += (size_t)256 * 32 * 2;
    ushort* e2wb = (ushort*)p; p += (size_t)256 * 1024 * 2;
    ushort* q1wt = (ushort*)p; p += (size_t)256 * 1024 * 2;
    ushort* q2wt = (ushort*)p; p += (size_t)32 * 256 * 2;

    // 0. weight prep: transposes, e2w bf16 copy, zeros, c2 = e2b@q1w
    misc_prep<<<538, 256, 0, stream>>>(kw, e1w, e2w, q1w, q2w, e2b,
                                       kwt, e1wt, e2wb, q1wt, q2wt, zeros, c2);

    // 1. key = ee @ kw + kb  (M=262144, N=32, K=256), fp32 A staged->bf16, KEYMODE out
    mfma_gemm<128, 32, 64, 4, 1, false, false, false, true, true>
        <<<dim3(2048, 1), 256, 0, stream>>>(ee, 256, kwt, kb, nullptr, 0, key, 32, 256, 0);

    // 2. P0 = ar @ q1w + q1b  (M=512, N=256, K=1024), fp32 out
    mfma_gemm<128, 128, 64, 2, 2, false, false, false, true, false>
        <<<dim3(4, 2), 256, 0, stream>>>(ar, 1024, q1wt, q1b, nullptr, 0, P0, 256, 1024, 0);

    // 3. W2t[j,k2] = (e2w@q1w)[k2,j]  (M=256, N=256, K=1024), bf16 out
    mfma_gemm<128, 128, 64, 2, 2, false, false, true, false, false>
        <<<dim3(2, 2), 256, 0, stream>>>(q1wt, 1024, e2wb, zeros, nullptr, 0, W2t, 256, 1024, 0);

    // 4. Y1 rows 0..511 = relu(P0)  (step 0: ae = ar)
    relu_y0<<<64, 256, 0, stream>>>(P0, Y1b);

    // 5. key fixup + fs + pooled EMB
    prep_kernel<<<512, 64, 0, stream>>>(en, su, sun, key, eemb, fs, EMBb);

    // 6. Z1 = relu(EMB @ e1w + e1b)   (M=32256, N=256, K=32)
    mfma_gemm<128, 128, 32, 2, 2, true, false, true, false, false>
        <<<dim3(252, 2), 256, 0, stream>>>(EMBb, 32, e1wt, e1b, nullptr, 0, Z1b, 256, 32, 0);

    // 7. Y1[512..] = relu(Z1 @ W2t^T + c2 + P0[b])  (M=32256, N=256, K=256)
    mfma_gemm<128, 128, 64, 2, 2, true, true, true, false, false>
        <<<dim3(252, 2), 256, 0, stream>>>(Z1b, 256, W2t, c2, P0, 256, Y1b, 256, 256, 512);

    // 8. X = Y1 @ q2w + q2b  (M=32768, N=32, K=256), fp32 out
    mfma_gemm<128, 32, 64, 4, 1, false, false, false, false, false>
        <<<dim3(256, 1), 256, 0, stream>>>(Y1b, 256, q2wt, q2b, nullptr, 0, X, 32, 256, 0);

    // 9. LN-LSTM over 64 steps -> queries (one wave per batch, barrier-free)
    lstm_kernel<<<256, 128, 0, stream>>>(X, wih, whh, lnig, lnib, lnhg, lnhb, lncg, lncb, Q);

    // 10. logits + mask
    logits_kernel<<<dim3(512, 5), 128, 0, stream>>>(key, Q, fs, en, outp);
}